// Round 4
// baseline (173.312 us; speedup 1.0000x reference)
//
#include <hip/hip_runtime.h>
#include <math.h>

#define N 4096
#define NFEAT 512
#define NHID 64
#define NHEADS 8
#define P_PAIRS 65536
#define CAP 128
#define LRELU_ALPHA 0.2f
#define KS1 4   // K-split for layer-1 gemm (K=512 -> 4 x 128)
#define KS2 8   // K-split for layer-2 gemm (K=512 -> 8 x 64)

// ---------------- K1: build CSR from dense adj (one pass over 67 MB) -------
__global__ __launch_bounds__(256) void build_csr(const float* __restrict__ adj,
                                                 int* __restrict__ counts,
                                                 int* __restrict__ cols) {
  int row = blockIdx.x;
  __shared__ int cnt;
  if (threadIdx.x == 0) cnt = 0;
  __syncthreads();
  const float4* arow = (const float4*)(adj + (size_t)row * N);
  for (int c4 = threadIdx.x; c4 < N / 4; c4 += 256) {
    float4 v = arow[c4];
    int base = c4 * 4;
    if (v.x > 0.f) { int k = atomicAdd(&cnt, 1); if (k < CAP) cols[(size_t)row * CAP + k] = base; }
    if (v.y > 0.f) { int k = atomicAdd(&cnt, 1); if (k < CAP) cols[(size_t)row * CAP + k] = base + 1; }
    if (v.z > 0.f) { int k = atomicAdd(&cnt, 1); if (k < CAP) cols[(size_t)row * CAP + k] = base + 2; }
    if (v.w > 0.f) { int k = atomicAdd(&cnt, 1); if (k < CAP) cols[(size_t)row * CAP + k] = base + 3; }
  }
  __syncthreads();
  if (threadIdx.x == 0) counts[row] = cnt < CAP ? cnt : CAP;
}

// ---------------- K2: f32 tiled GEMM with K-split --------------------------
// C_partial[z][M x 64] (+= over k-chunk z). blockIdx.y picks B block / C col
// offset; blockIdx.z picks the K chunk. Each block: 64x64 tile, kc of K.
__global__ __launch_bounds__(256) void gemm_ks(const float* __restrict__ A, int lda,
                                               const float* __restrict__ B, size_t bBlock,
                                               float* __restrict__ P, size_t ksBlock,
                                               int cOff, int ldc, int kc) {
  __shared__ float As[16][68];
  __shared__ float Bs[16][64];
  const float* Bp = B + (size_t)blockIdx.y * bBlock;
  float* Cp = P + (size_t)blockIdx.z * ksBlock + (size_t)blockIdx.y * cOff;
  int m0 = blockIdx.x * 64;
  int t = threadIdx.x;
  int tx = t & 15, ty = t >> 4;
  int lam = t >> 2;         // 0..63 : A-tile row
  int lak = (t & 3) * 4;    // 0,4,8,12 : A-tile k quad
  int lbk = t >> 4;         // 0..15 : B-tile k
  int lbn = (t & 15) * 4;   // B-tile col quad
  int kbase = blockIdx.z * kc;
  float acc[4][4] = {};
  for (int k0 = kbase; k0 < kbase + kc; k0 += 16) {
    float4 av = *(const float4*)(A + (size_t)(m0 + lam) * lda + k0 + lak);
    float4 bv = *(const float4*)(Bp + (size_t)(k0 + lbk) * 64 + lbn);
    As[lak + 0][lam] = av.x;
    As[lak + 1][lam] = av.y;
    As[lak + 2][lam] = av.z;
    As[lak + 3][lam] = av.w;
    *(float4*)(&Bs[lbk][lbn]) = bv;
    __syncthreads();
#pragma unroll
    for (int k = 0; k < 16; ++k) {
      float4 a = *(const float4*)(&As[k][ty * 4]);
      float4 b = *(const float4*)(&Bs[k][tx * 4]);
      float ar[4] = {a.x, a.y, a.z, a.w};
      float br[4] = {b.x, b.y, b.z, b.w};
#pragma unroll
      for (int i = 0; i < 4; i++)
#pragma unroll
        for (int j = 0; j < 4; j++)
          acc[i][j] = fmaf(ar[i], br[j], acc[i][j]);
    }
    __syncthreads();
  }
#pragma unroll
  for (int i = 0; i < 4; i++) {
    float4 o = {acc[i][0], acc[i][1], acc[i][2], acc[i][3]};
    *(float4*)(Cp + (size_t)(m0 + ty * 4 + i) * ldc + tx * 4) = o;
  }
}

// ---------------- K3a: layer-1 fused reduce + e_src/e_dst + col-sum --------
// part: KS1 slabs of [N][512] (heads interleaved). 128 blocks x 32 rows.
// Wave w handles cols [128w,128w+128) = heads 2w, 2w+1 (d = lane).
__global__ __launch_bounds__(256) void fuse1(const float* __restrict__ part,
                                             const float* __restrict__ a,
                                             float* __restrict__ Wh,
                                             float* __restrict__ esrc,
                                             float* __restrict__ edst,
                                             float* __restrict__ colpart) {
  int t = threadIdx.x;
  int w = t >> 6, lane = t & 63;
  int c0 = w * 128 + lane, c1 = c0 + 64;
  int h0 = 2 * w, h1 = 2 * w + 1;
  float as0 = a[h0 * 128 + lane], ad0 = a[h0 * 128 + 64 + lane];
  float as1 = a[h1 * 128 + lane], ad1 = a[h1 * 128 + 64 + lane];
  float cs0 = 0.f, cs1 = 0.f;
  int i0 = blockIdx.x * 32;
  for (int r = 0; r < 32; ++r) {
    int i = i0 + r;
    size_t base = (size_t)i * 512;
    float v0 = 0.f, v1 = 0.f;
#pragma unroll
    for (int z = 0; z < KS1; ++z) {
      v0 += part[(size_t)z * N * 512 + base + c0];
      v1 += part[(size_t)z * N * 512 + base + c1];
    }
    Wh[base + c0] = v0;
    Wh[base + c1] = v1;
    cs0 += v0;
    cs1 += v1;
    float s0 = v0 * as0, d0 = v0 * ad0;
    float s1 = v1 * as1, d1 = v1 * ad1;
#pragma unroll
    for (int off = 32; off; off >>= 1) {
      s0 += __shfl_xor(s0, off);
      d0 += __shfl_xor(d0, off);
      s1 += __shfl_xor(s1, off);
      d1 += __shfl_xor(d1, off);
    }
    if (lane == 0) {
      esrc[h0 * N + i] = s0;
      edst[h0 * N + i] = d0;
      esrc[h1 * N + i] = s1;
      edst[h1 * N + i] = d1;
    }
  }
  colpart[(size_t)blockIdx.x * 512 + c0] = cs0;
  colpart[(size_t)blockIdx.x * 512 + c1] = cs1;
}

// ---------------- K3b: layer-2 fused reduce + e + col-sum ------------------
// part: KS2 slabs of [N][64]. 128 blocks x 32 rows; wave w rows w*8..w*8+7.
__global__ __launch_bounds__(256) void fuse2(const float* __restrict__ part,
                                             const float* __restrict__ a,
                                             float* __restrict__ Wh,
                                             float* __restrict__ esrc,
                                             float* __restrict__ edst,
                                             float* __restrict__ colpart) {
  int t = threadIdx.x;
  int w = t >> 6, lane = t & 63;
  float as = a[lane], ad = a[64 + lane];
  float cs = 0.f;
  int i0 = blockIdx.x * 32 + w * 8;
  for (int r = 0; r < 8; ++r) {
    int i = i0 + r;
    size_t base = (size_t)i * 64;
    float v = 0.f;
#pragma unroll
    for (int z = 0; z < KS2; ++z) v += part[(size_t)z * N * 64 + base + lane];
    Wh[base + lane] = v;
    cs += v;
    float s = v * as, d = v * ad;
#pragma unroll
    for (int off = 32; off; off >>= 1) {
      s += __shfl_xor(s, off);
      d += __shfl_xor(d, off);
    }
    if (lane == 0) {
      esrc[i] = s;
      edst[i] = d;
    }
  }
  colpart[((size_t)blockIdx.x * 4 + w) * 64 + lane] = cs;
}

// ---------------- K4: fold column-sum partials (J slabs of C cols) ---------
__global__ __launch_bounds__(256) void col_sum_final(const float* __restrict__ partial,
                                                     int C, int J,
                                                     float* __restrict__ out) {
  int col = blockIdx.x * 64 + (threadIdx.x & 63);
  int q = threadIdx.x >> 6;
  int per = J / 4;
  float s = 0.f;
  for (int j = q * per; j < (q + 1) * per; ++j) s += partial[(size_t)j * C + col];
  __shared__ float red[4][64];
  red[q][threadIdx.x & 63] = s;
  __syncthreads();
  if (q == 0)
    out[col] = red[0][threadIdx.x] + red[1][threadIdx.x] + red[2][threadIdx.x] +
               red[3][threadIdx.x];
}

// ---------------- K5a: layer-1 attention, one block (8 waves) per node -----
__global__ __launch_bounds__(512) void gat_attn_l1(const float* __restrict__ Wh,
                                                   const float* __restrict__ esrc,
                                                   const float* __restrict__ edst,
                                                   const int* __restrict__ counts,
                                                   const int* __restrict__ cols,
                                                   const float* __restrict__ sumWh,
                                                   float* __restrict__ out) {
  int i = blockIdx.x;
  int tid = threadIdx.x;
  int lane = tid & 63;
  int h = tid >> 6;
  int cnt = counts[i];
  __shared__ int jls[CAP];
  __shared__ float pls[NHEADS][CAP];
  float acc = 0.f;
  if (cnt == 0) {
    acc = sumWh[tid] * (1.0f / N);  // softmax over uniform NEG row
  } else {
    if (tid < cnt) jls[tid] = cols[(size_t)i * CAP + tid];
    __syncthreads();
    float ei = esrc[h * N + i];
    const float* ed = edst + (size_t)h * N;
    float e0 = -1e30f, e1 = -1e30f;
    if (lane < cnt) {
      float e = ei + ed[jls[lane]];
      e0 = (e > 0.f) ? e : LRELU_ALPHA * e;
    }
    if (lane + 64 < cnt) {
      float e = ei + ed[jls[lane + 64]];
      e1 = (e > 0.f) ? e : LRELU_ALPHA * e;
    }
    float m = fmaxf(e0, e1);
#pragma unroll
    for (int off = 32; off; off >>= 1) m = fmaxf(m, __shfl_xor(m, off));
    float p0 = (lane < cnt) ? __expf(e0 - m) : 0.f;
    float p1 = (lane + 64 < cnt) ? __expf(e1 - m) : 0.f;
    float ssum = p0 + p1;
#pragma unroll
    for (int off = 32; off; off >>= 1) ssum += __shfl_xor(ssum, off);
    pls[h][lane] = p0;
    pls[h][lane + 64] = p1;  // own-wave write->read
    int k = 0;
    for (; k + 4 <= cnt; k += 4) {
      int ja = jls[k + 0], jb = jls[k + 1], jc = jls[k + 2], jd = jls[k + 3];
      float pa = pls[h][k + 0], pb = pls[h][k + 1];
      float pc = pls[h][k + 2], pd = pls[h][k + 3];
      float va = Wh[((size_t)ja << 9) + tid];
      float vb = Wh[((size_t)jb << 9) + tid];
      float vc = Wh[((size_t)jc << 9) + tid];
      float vd = Wh[((size_t)jd << 9) + tid];
      acc = fmaf(pa, va, acc);
      acc = fmaf(pb, vb, acc);
      acc = fmaf(pc, vc, acc);
      acc = fmaf(pd, vd, acc);
    }
    for (; k < cnt; ++k)
      acc = fmaf(pls[h][k], Wh[((size_t)jls[k] << 9) + tid], acc);
    acc /= ssum;
  }
  acc = (acc > 0.f) ? acc : expm1f(acc);  // ELU
  out[((size_t)i << 9) + tid] = acc;
}

// ---------------- K5b: layer-2 attention, one wave per node ----------------
__global__ __launch_bounds__(256) void gat_attn_l2(const float* __restrict__ Wh,
                                                   const float* __restrict__ esrc,
                                                   const float* __restrict__ edst,
                                                   const int* __restrict__ counts,
                                                   const int* __restrict__ cols,
                                                   const float* __restrict__ sumWh,
                                                   float* __restrict__ out) {
  int wv = threadIdx.x >> 6;
  int lane = threadIdx.x & 63;
  int i = (blockIdx.x << 2) + wv;
  int cnt = counts[i];
  __shared__ int jls[4][CAP];
  __shared__ float pls[4][CAP];
  float acc = 0.f;
  if (cnt == 0) {
    acc = sumWh[lane] * (1.0f / N);
  } else {
    const int* cl = cols + (size_t)i * CAP;
    if (lane < cnt) jls[wv][lane] = cl[lane];
    if (lane + 64 < cnt) jls[wv][lane + 64] = cl[lane + 64];
    float ei = esrc[i];
    float e0 = -1e30f, e1 = -1e30f;
    if (lane < cnt) {
      float e = ei + edst[jls[wv][lane]];
      e0 = (e > 0.f) ? e : LRELU_ALPHA * e;
    }
    if (lane + 64 < cnt) {
      float e = ei + edst[jls[wv][lane + 64]];
      e1 = (e > 0.f) ? e : LRELU_ALPHA * e;
    }
    float m = fmaxf(e0, e1);
#pragma unroll
    for (int off = 32; off; off >>= 1) m = fmaxf(m, __shfl_xor(m, off));
    float p0 = (lane < cnt) ? __expf(e0 - m) : 0.f;
    float p1 = (lane + 64 < cnt) ? __expf(e1 - m) : 0.f;
    float ssum = p0 + p1;
#pragma unroll
    for (int off = 32; off; off >>= 1) ssum += __shfl_xor(ssum, off);
    pls[wv][lane] = p0;
    pls[wv][lane + 64] = p1;
    int k = 0;
    for (; k + 4 <= cnt; k += 4) {
      int ja = jls[wv][k + 0], jb = jls[wv][k + 1];
      int jc = jls[wv][k + 2], jd = jls[wv][k + 3];
      float pa = pls[wv][k + 0], pb = pls[wv][k + 1];
      float pc = pls[wv][k + 2], pd = pls[wv][k + 3];
      float va = Wh[((size_t)ja << 6) + lane];
      float vb = Wh[((size_t)jb << 6) + lane];
      float vc = Wh[((size_t)jc << 6) + lane];
      float vd = Wh[((size_t)jd << 6) + lane];
      acc = fmaf(pa, va, acc);
      acc = fmaf(pb, vb, acc);
      acc = fmaf(pc, vc, acc);
      acc = fmaf(pd, vd, acc);
    }
    for (; k < cnt; ++k)
      acc = fmaf(pls[wv][k], Wh[((size_t)jls[wv][k] << 6) + lane], acc);
    acc /= ssum;
  }
  acc = (acc > 0.f) ? acc : expm1f(acc);  // ELU
  out[((size_t)i << 6) + lane] = acc;
}

// ---------------- K6: pairwise bilinear scores (4 pairs/wave, float4) ------
__global__ __launch_bounds__(256) void score_quad(const float* __restrict__ g,
                                                  const float* __restrict__ hf,
                                                  const int* __restrict__ p1,
                                                  const int* __restrict__ p2,
                                                  float* __restrict__ out) {
  int w = threadIdx.x >> 6;
  int lane = threadIdx.x & 63;
  int sub = lane >> 4, sl = lane & 15;
  int p = (((blockIdx.x << 2) + w) << 2) + sub;
  int i1 = p1[p], i2 = p2[p];
  float4 ga = *(const float4*)(g + ((size_t)i1 << 6) + sl * 4);
  float4 hb = *(const float4*)(hf + ((size_t)i2 << 6) + sl * 4);
  float v = ga.x * hb.x + ga.y * hb.y + ga.z * hb.z + ga.w * hb.w;
#pragma unroll
  for (int off = 8; off; off >>= 1) v += __shfl_xor(v, off);
  if (sl == 0) out[p] = v;
}

extern "C" void kernel_launch(void* const* d_in, const int* in_sizes, int n_in,
                              void* d_out, int out_size, void* d_ws, size_t ws_size,
                              hipStream_t stream) {
  const float* x       = (const float*)d_in[0];
  const float* adj     = (const float*)d_in[1];
  const float* W_heads = (const float*)d_in[2];
  const float* a_heads = (const float*)d_in[3];
  const float* W_out   = (const float*)d_in[4];
  const float* a_out   = (const float*)d_in[5];
  const float* W_score = (const float*)d_in[6];
  const int* p1        = (const int*)d_in[7];
  const int* p2        = (const int*)d_in[8];
  float* out           = (float*)d_out;

  char* ws = (char*)d_ws;
  size_t off = 0;
  auto alloc = [&](size_t bytes) -> void* {
    void* p = ws + off;
    off += (bytes + 255) & ~(size_t)255;
    return p;
  };
  int*   counts = (int*)alloc((size_t)N * 4);
  int*   cols   = (int*)alloc((size_t)N * CAP * 4);
  float* Wh1    = (float*)alloc((size_t)N * 512 * 4);   // [N][8*64] interleaved
  float* es1    = (float*)alloc((size_t)NHEADS * N * 4);
  float* ed1    = (float*)alloc((size_t)NHEADS * N * 4);
  float* sum1   = (float*)alloc((size_t)512 * 4);
  float* partA  = (float*)alloc((size_t)KS1 * N * 512 * 4);  // 32 MB
  float* cpart1 = (float*)alloc((size_t)128 * 512 * 4);
  float* h1     = (float*)alloc((size_t)N * 512 * 4);
  float* Wh2    = (float*)alloc((size_t)N * 64 * 4);
  float* es2    = (float*)alloc((size_t)N * 4);
  float* ed2    = (float*)alloc((size_t)N * 4);
  float* sum2   = (float*)alloc((size_t)64 * 4);
  float* partB  = (float*)alloc((size_t)KS2 * N * 64 * 4);   // 8 MB
  float* cpart2 = (float*)alloc((size_t)512 * 64 * 4);
  float* hf     = (float*)alloc((size_t)N * 64 * 4);
  float* g      = (float*)alloc((size_t)N * 64 * 4);

  // adjacency -> CSR (shared by both layers)
  build_csr<<<N, 256, 0, stream>>>(adj, counts, cols);

  // ---- layer 1 (8 heads, interleaved Wh1 [N][512]) ----
  gemm_ks<<<dim3(N / 64, NHEADS, KS1), 256, 0, stream>>>(
      x, NFEAT, W_heads, (size_t)NFEAT * 64, partA, (size_t)N * 512, 64, 512,
      NFEAT / KS1);
  fuse1<<<128, 256, 0, stream>>>(partA, a_heads, Wh1, es1, ed1, cpart1);
  col_sum_final<<<8, 256, 0, stream>>>(cpart1, 512, 128, sum1);
  gat_attn_l1<<<N, 512, 0, stream>>>(Wh1, es1, ed1, counts, cols, sum1, h1);

  // ---- layer 2 (1 head) ----
  gemm_ks<<<dim3(N / 64, 1, KS2), 256, 0, stream>>>(
      h1, 512, W_out, 0, partB, (size_t)N * 64, 0, 64, 512 / KS2);
  fuse2<<<128, 256, 0, stream>>>(partB, a_out, Wh2, es2, ed2, cpart2);
  col_sum_final<<<1, 256, 0, stream>>>(cpart2, 64, 512, sum2);
  gat_attn_l2<<<N / 4, 256, 0, stream>>>(Wh2, es2, ed2, counts, cols, sum2, hf);

  // ---- pairwise scores ----
  gemm_ks<<<dim3(N / 64, 1, 1), 256, 0, stream>>>(hf, 64, W_score, 0, g,
                                                  0, 0, 64, 64);
  score_quad<<<P_PAIRS / 16, 256, 0, stream>>>(g, hf, p1, p2, out);
}